// Round 6
// baseline (83.028 us; speedup 1.0000x reference)
//
#include <hip/hip_runtime.h>

// out[i][j] = sign(sign_vector[i]) * H[i][j], N = 8192, all float32.
// R4 (passed, 82.4us): cacheable loads (L3 keeps half of H resident across
// replays, FETCH=134MB) + builtin-nt stores. Real HBM traffic 402MB @ 4.9TB/s
// => not yet BW-bound; likely MLP-bound (8 loads in flight, then vmcnt stall).
// R5 (sc0/sc1 asm store) FAILED correctness - reverted; builtin nt store only.
// This round: 2 rows per block -> 16 independent 16B loads in flight per lane
// (256 B/lane) before stores. Flags identical to R4.

#define HN 8192
#define ROW4 (HN / 4)         // 2048 vec4 per row
#define PAIR4 (2 * ROW4)      // 4096 vec4 per 2-row block; /256 thr = 16 each

typedef float vfloat4 __attribute__((ext_vector_type(4)));

__global__ __launch_bounds__(256) void binadamard_sign_mul_kernel(
    const float* __restrict__ sv,
    const float* __restrict__ H,
    float* __restrict__ out) {
    const int rpair = blockIdx.x;  // rows 2*rpair, 2*rpair+1

    // exact jnp.sign semantics: +1 / -1 / 0 (broadcast reads, L1-resident)
    const float v0 = sv[2 * rpair];
    const float v1 = sv[2 * rpair + 1];
    const float s0 = (v0 > 0.0f) ? 1.0f : ((v0 < 0.0f) ? -1.0f : 0.0f);
    const float s1 = (v1 > 0.0f) ? 1.0f : ((v1 < 0.0f) ? -1.0f : 0.0f);

    const vfloat4* __restrict__ H4 =
        reinterpret_cast<const vfloat4*>(H) + (long long)rpair * PAIR4;
    vfloat4* __restrict__ O4 =
        reinterpret_cast<vfloat4*>(out) + (long long)rpair * PAIR4;

    const int t = threadIdx.x;

    // 16 independent loads in flight (first 8 -> row0, last 8 -> row1)
    vfloat4 h[16];
#pragma unroll
    for (int j = 0; j < 16; ++j) {
        h[j] = H4[j * 256 + t];  // cacheable: allow L2/L3 allocation for reuse
    }

#pragma unroll
    for (int j = 0; j < 16; ++j) {
        const float s = (j < 8) ? s0 : s1;
        vfloat4 o = s * h[j];
        __builtin_nontemporal_store(o, &O4[j * 256 + t]);  // streaming write
    }
}

extern "C" void kernel_launch(void* const* d_in, const int* in_sizes, int n_in,
                              void* d_out, int out_size, void* d_ws, size_t ws_size,
                              hipStream_t stream) {
    // inputs in setup_inputs() order: weight (ignored), sign_vector, block_hadamard_kernel
    const float* sv = (const float*)d_in[1];
    const float* H  = (const float*)d_in[2];
    float* out = (float*)d_out;

    binadamard_sign_mul_kernel<<<HN / 2, 256, 0, stream>>>(sv, H, out);
}